// Round 4
// baseline (94.415 us; speedup 1.0000x reference)
//
#include <hip/hip_runtime.h>
#include <hip/hip_bf16.h>

// PtrNet2: B=512, T=2048, IN=2, H=128
// Algebraic collapse (IN=2): u2[b,h,t] = mask*(x0*P0[h]+x1*P1[h]+E[h]) + wrefB[h],
//   glimpse readout = X0*P0 + X1*P1 + C*E + wrefB with X0=sum a*m*x0, X1=sum a*m*x1, C=sum a*m.
// tanh fold: sum_h vec*tanh = Vsum - sum_h (2vec)*rcp(exp2(c*arg)+1), c=2*log2(e).
// Softmax shift-invariance: weights ∝ exp(-acc); |acc| ≤ sum|2vec| ≈ 13 → no max pass needed.
// R4: 1024-thr blocks (TOK=2) → 32 waves/CU; inner loop = 1 ds_read_b128 (cf) +
// v_readlane (2vec from lane-resident regs) + 5 VALU + 2 trans per token. No s_loads.

#define Bsz 512
#define Tsz 2048
#define Hsz 128
#define TPB 1024
#define TOK 2  // Tsz / TPB

#define C2LOG2E 2.8853900817779268f
#define LOG2E   1.4426950408889634f

__device__ __forceinline__ float exp2fast(float x) { return __builtin_amdgcn_exp2f(x); }
__device__ __forceinline__ float rcpfast(float x)  { return __builtin_amdgcn_rcpf(x); }
__device__ __forceinline__ float readlanef(float v, int l) {
    return __uint_as_float(__builtin_amdgcn_readlane(__float_as_uint(v), l));
}

// ---- kprep: SC={c*P0,c*P1,c*E,c*(u1g0+wrefB)}, V2G=2*vec, UC={P0,P1,E,wrefB} ----
__global__ __launch_bounds__(128) void kprep(
        const float* __restrict__ embW, const float* __restrict__ embB,
        const float* __restrict__ encW, const float* __restrict__ encB,
        const float* __restrict__ wrefW, const float* __restrict__ wrefB,
        const float* __restrict__ wqW, const float* __restrict__ wqB,
        const float* __restrict__ dec, const float* __restrict__ vec,
        float4* __restrict__ SC, float* __restrict__ V2G, float4* __restrict__ UC) {
    __shared__ float m0[Hsz], m1[Hsz], cc[Hsz], dq[Hsz];
    int h = threadIdx.x;
    float a0 = 0.f, a1 = 0.f, ac = 0.f;
    for (int k = 0; k < Hsz; ++k) {
        float w = encW[h * Hsz + k];
        a0 = fmaf(w, embW[2 * k + 0], a0);
        a1 = fmaf(w, embW[2 * k + 1], a1);
        ac = fmaf(w, embB[k], ac);
    }
    m0[h] = a0; m1[h] = a1; cc[h] = ac + encB[h]; dq[h] = dec[h];
    __syncthreads();
    float p0 = 0.f, p1 = 0.f, pe = 0.f, uq = wqB[h];
    for (int k = 0; k < Hsz; ++k) {
        float w = wrefW[h * Hsz + k];
        p0 = fmaf(w, m0[k], p0);
        p1 = fmaf(w, m1[k], p1);
        pe = fmaf(w, cc[k], pe);
        uq = fmaf(wqW[h * Hsz + k], dq[k], uq);
    }
    float wb = wrefB[h];
    SC[h]  = make_float4(C2LOG2E * p0, C2LOG2E * p1, C2LOG2E * pe, C2LOG2E * (uq + wb));
    V2G[h] = 2.f * vec[h];
    UC[h]  = make_float4(p0, p1, pe, wb);
}

// ---- fused: one 1024-thread block per batch row; both glimpses + final head ----
__global__ __launch_bounds__(TPB, 8) void kfused(
        const float* __restrict__ x, const float* __restrict__ mask,
        const float4* __restrict__ SC, const float* __restrict__ V2G,
        const float4* __restrict__ UC,
        const float* __restrict__ wqW, const float* __restrict__ wqB,
        const float* __restrict__ fc1, const float* __restrict__ fc2,
        float* __restrict__ out) {
    __shared__ float4 cf[Hsz];   // {c*P0, c*P1, c*E, base}; .w updated in place for glimpse 1
    __shared__ float4 uc[Hsz];   // {P0, P1, E, wrefB}
    __shared__ float q[Hsz], rr[Hsz];
    __shared__ float pp[8][Hsz];
    __shared__ float4 red4[16];
    __shared__ float4 tripS;

    int b = blockIdx.x, tid = threadIdx.x;
    int wave = tid >> 6, lane = tid & 63;
    if (tid < Hsz) { cf[tid] = SC[tid]; uc[tid] = UC[tid]; }
    // grid-constant 2*vec, lane-resident: h = lane (vvA) and 64+lane (vvB)
    float vvA = V2G[lane], vvB = V2G[64 + lane];

    const float2* x2 = (const float2*)(x + (size_t)b * Tsz * 2);
    const float* mrow = mask + (size_t)b * Tsz;
    float xm0[TOK], xm1[TOK], mk[TOK], xr0[TOK], xr1[TOK];
    #pragma unroll
    for (int j = 0; j < TOK; ++j) {
        float2 xv = x2[j * TPB + tid];
        float m = mrow[j * TPB + tid];
        mk[j] = m; xr0[j] = xv.x; xr1[j] = xv.y;
        xm0[j] = xv.x * m; xm1[j] = xv.y * m;
    }
    __syncthreads();

    float X0 = 0.f, X1 = 0.f, Cm = 0.f;
    #pragma unroll 1
    for (int g = 0; g < 2; ++g) {
        // ---- score: acc[j] = sum_h (2vec_h)*rcp(exp2(affine)+1) ----
        float acc0 = 0.f, acc1 = 0.f;
        #pragma unroll 8
        for (int h = 0; h < 64; ++h) {
            float4 cv = cf[h];
            float vv = readlanef(vvA, h);
            float a0 = fmaf(xm0[0], cv.x, fmaf(xm1[0], cv.y, fmaf(mk[0], cv.z, cv.w)));
            acc0 = fmaf(vv, rcpfast(exp2fast(a0) + 1.f), acc0);
            float a1 = fmaf(xm0[1], cv.x, fmaf(xm1[1], cv.y, fmaf(mk[1], cv.z, cv.w)));
            acc1 = fmaf(vv, rcpfast(exp2fast(a1) + 1.f), acc1);
        }
        #pragma unroll 8
        for (int h = 64; h < 128; ++h) {
            float4 cv = cf[h];
            float vv = readlanef(vvB, h - 64);
            float a0 = fmaf(xm0[0], cv.x, fmaf(xm1[0], cv.y, fmaf(mk[0], cv.z, cv.w)));
            acc0 = fmaf(vv, rcpfast(exp2fast(a0) + 1.f), acc0);
            float a1 = fmaf(xm0[1], cv.x, fmaf(xm1[1], cv.y, fmaf(mk[1], cv.z, cv.w)));
            acc1 = fmaf(vv, rcpfast(exp2fast(a1) + 1.f), acc1);
        }
        // ---- weights ∝ exp(-acc); no shift needed (|acc| ≤ ~13, fp32-safe) ----
        float e0 = exp2fast(-LOG2E * acc0), e1 = exp2fast(-LOG2E * acc1);
        float em0 = e0 * mk[0], em1 = e1 * mk[1];
        float Z = e0 + e1, Sm = em0 + em1;
        float S0 = fmaf(em0, xr0[0], em1 * xr0[1]);
        float S1 = fmaf(em0, xr1[0], em1 * xr1[1]);
        for (int off = 32; off; off >>= 1) {
            Z += __shfl_xor(Z, off); Sm += __shfl_xor(Sm, off);
            S0 += __shfl_xor(S0, off); S1 += __shfl_xor(S1, off);
        }
        if (lane == 0) red4[wave] = make_float4(Z, Sm, S0, S1);
        __syncthreads();
        if (tid < 16) {
            float4 v = red4[tid];
            for (int off = 8; off; off >>= 1) {
                v.x += __shfl_xor(v.x, off); v.y += __shfl_xor(v.y, off);
                v.z += __shfl_xor(v.z, off); v.w += __shfl_xor(v.w, off);
            }
            if (tid == 0) {
                float inv = 1.f / v.x;
                tripS = make_float4(v.z * inv, v.w * inv, v.y * inv, 0.f);
            }
        }
        __syncthreads();
        X0 = tripS.x; X1 = tripS.y; Cm = tripS.z;

        if (g == 0) {
            // ---- glimpse-1 query + u1 = wqW@q + wqB; cf[h].w := c*(u1+wrefB) ----
            if (tid < Hsz) {
                float4 u4 = uc[tid];
                q[tid] = fmaf(X0, u4.x, fmaf(X1, u4.y, fmaf(Cm, u4.z, u4.w)));
            }
            __syncthreads();
            {
                int h = tid & (Hsz - 1), part = tid >> 7;   // 8 parts x 16 k
                float s = 0.f;
                const float* wr = wqW + (size_t)h * Hsz + part * 16;
                #pragma unroll
                for (int k = 0; k < 16; ++k) s = fmaf(wr[k], q[part * 16 + k], s);
                pp[part][h] = s;
            }
            __syncthreads();
            if (tid < Hsz) {
                float u1h = wqB[tid];
                #pragma unroll
                for (int p = 0; p < 8; ++p) u1h += pp[p][tid];
                cf[tid].w = C2LOG2E * (u1h + uc[tid].w);
            }
            __syncthreads();
        }
    }
    // ---- final head: q2 -> relu(fc1 @ q2) -> fc2 ----
    if (tid < Hsz) {
        float4 u4 = uc[tid];
        q[tid] = fmaf(X0, u4.x, fmaf(X1, u4.y, fmaf(Cm, u4.z, u4.w)));
    }
    __syncthreads();
    {
        int h = tid & (Hsz - 1), part = tid >> 7;
        float s = 0.f;
        const float* fr = fc1 + (size_t)h * Hsz + part * 16;
        #pragma unroll
        for (int k = 0; k < 16; ++k) s = fmaf(fr[k], q[part * 16 + k], s);
        pp[part][h] = s;
    }
    __syncthreads();
    if (tid < Hsz) {
        float s = 0.f;
        #pragma unroll
        for (int p = 0; p < 8; ++p) s += pp[p][tid];
        rr[tid] = fmaxf(0.f, s);
    }
    __syncthreads();
    if (tid < 128) {
        int o = tid >> 6, l = tid & 63;
        float s = fc2[o * Hsz + l] * rr[l] + fc2[o * Hsz + 64 + l] * rr[64 + l];
        for (int off = 32; off; off >>= 1) s += __shfl_xor(s, off);
        if (l == 0) out[b * 2 + o] = s;
    }
}

extern "C" void kernel_launch(void* const* d_in, const int* in_sizes, int n_in,
                              void* d_out, int out_size, void* d_ws, size_t ws_size,
                              hipStream_t stream) {
    const float* x     = (const float*)d_in[0];
    const float* mask  = (const float*)d_in[1];
    const float* embW  = (const float*)d_in[2];
    const float* embB  = (const float*)d_in[3];
    const float* encW  = (const float*)d_in[4];
    const float* encB  = (const float*)d_in[5];
    const float* dec   = (const float*)d_in[6];
    const float* vec   = (const float*)d_in[7];
    const float* wqW   = (const float*)d_in[8];
    const float* wqB   = (const float*)d_in[9];
    const float* wrefW = (const float*)d_in[10];
    const float* wrefB = (const float*)d_in[11];
    const float* fc1   = (const float*)d_in[12];
    const float* fc2   = (const float*)d_in[13];

    float* ws = (float*)d_ws;
    float4* SC = (float4*)ws;            // 128 float4
    float4* UC = (float4*)(ws + 512);    // 128 float4
    float* V2G = ws + 1024;              // 128 floats
    float* out = (float*)d_out;

    kprep<<<1, 128, 0, stream>>>(embW, embB, encW, encB, wrefW, wrefB, wqW, wqB,
                                 dec, vec, SC, V2G, UC);
    kfused<<<Bsz, TPB, 0, stream>>>(x, mask, SC, V2G, UC, wqW, wqB, fc1, fc2, out);
}